// Round 7
// baseline (235.959 us; speedup 1.0000x reference)
//
#include <hip/hip_runtime.h>
#include <hip/hip_bf16.h>
#include <math.h>

#define DIM   768
#define CA    192

typedef __attribute__((ext_vector_type(8))) short short8;
typedef __attribute__((ext_vector_type(4))) float f32x4;

static __device__ __forceinline__ short f2bf(float f) {
    union { __hip_bfloat16 b; short s; } u;
    u.b = __float2bfloat16(f);
    return u.s;
}
static __device__ __forceinline__ float gelu_exact(float x) {
    return 0.5f * x * (1.0f + erff(x * 0.70710678118654752440f));
}
// async global->LDS DMA, 16B per lane; lds base must be wave-uniform.
static __device__ __forceinline__ void ld16(void* lds, const void* gsrc) {
    __builtin_amdgcn_global_load_lds((const __attribute__((address_space(1))) void*)gsrc,
                                     (__attribute__((address_space(3))) void*)lds, 16, 0, 0);
}

// ---------------------------------------------------------------------------
// Prep: w1 (768,192) -> w1T (192,768) bf16; w2 (192,768) -> w2T (768,192) bf16
// ---------------------------------------------------------------------------
__global__ void prep_kernel(const float* __restrict__ w1, const float* __restrict__ w2,
                            short* __restrict__ w1T, short* __restrict__ w2T) {
    int idx = blockIdx.x * 256 + threadIdx.x;
    if (idx < CA * DIM) {
        int n = idx / DIM, k = idx - n * DIM;
        w1T[idx] = f2bf(w1[k * CA + n]);
        int n2 = idx / CA, k2 = idx - n2 * CA;
        w2T[idx] = f2bf(w2[k2 * DIM + n2]);
    }
}

// ---------------------------------------------------------------------------
// Fused GEMM1 + temporal mix + gelu -> g (bf16).
// Tile 32 rows x 192 cols (full N), K=768, BK=32, 24 iters. Grid 784 =
// 196 l x 4 row-quarters. 4 waves 2m x 2n, wave tile 16x96.
// BOTH operands staged via global_load_lds, 3 stages x 16KB = 48KB ->
// 3 blocks/CU. A staged as RAW F32 (no xcvt prepass); f32->bf16 cvt at
// fragment-read time (16 VALU/iter, hidden under MFMA).
// Counted vmcnt (T3+T4): uniform 4 DMA instrs per wave per stage
// (wave 0: A 4x1KB; waves 1-3: B 4x1KB each); ONE barrier per iter;
// steady-state wait vmcnt(4) (stage t+1 in flight), vmcnt(0) only at t=23.
// LDS plane layout (conflict-free, no XOR, DMA-linear):
//   A: 8 k-chunk planes x 32 rows x 16B (f32x4)  -> slot = c*32 + m
//   B: 4 k-chunk planes x 192 rows x 16B (bf16x8)-> slot = q*192 + rB
//   frag reads hit consecutive rows within a plane -> consecutive 16B
//   slots -> 8 banks per 16 lanes = 2-way (free).
// Epilogue (verified R0/R4): res via shfl_xor(16); l==1 writes token-0 rows.
// ---------------------------------------------------------------------------
__global__ __launch_bounds__(256, 3) void gemm1_fused(
        const float* __restrict__ x, const short* __restrict__ w1T,
        const float* __restrict__ b1, const float* __restrict__ conv_w,
        const float* __restrict__ conv_b, short* __restrict__ gq) {
    __shared__ __align__(16) short lds[3][8192];    // 16KB/stage: A 4KB + B 12KB

    const int tid = threadIdx.x;
    const int bx  = blockIdx.x;
    const int l   = (bx >> 2) + 1;
    const int hm  = bx & 3;
    const int R0  = l * 128 + hm * 32;

    const int wave = tid >> 6, lane = tid & 63;
    const int wm = wave >> 1, wn = wave & 1;
    const int lm = lane & 15, lg = lane >> 4;

    // DMA assignment: 16 instrs/stage, 4 per wave. Wave 0 -> A, waves 1-3 -> B.
    const char* src[4];
    int loff[4];                                     // in shorts
    const int step = (wave == 0) ? 128 : 64;         // source bytes per K-stage
    #pragma unroll
    for (int j = 0; j < 4; j++) {
        if (wave == 0) {                             // A: slot il = c*32 + m
            int il = j * 64 + lane;                  // 0..255
            int c = il >> 5, m = il & 31;
            src[j]  = (const char*)(x + (size_t)(R0 + m) * DIM + c * 4);
            loff[j] = il * 8;
        } else {                                     // B: slot il = q*192 + rB
            int il = (wave - 1) * 4 * 64 + j * 64 + lane;   // 0..767
            int q = il / 192, rB = il - q * 192;
            src[j]  = (const char*)(w1T + (size_t)rB * DIM + q * 8);
            loff[j] = 2048 + il * 8;
        }
    }

    f32x4 acc[6] = {};

    auto STAGE = [&](int t, int buf) {
        #pragma unroll
        for (int j = 0; j < 4; j++)
            ld16(&lds[buf][loff[j]], src[j] + (size_t)t * step);
    };

    STAGE(0, 0);
    STAGE(1, 1);

    #pragma unroll
    for (int t = 0; t < 24; t++) {
        // retire stage t (4 own ops); stage t+1's 4 ops stay in flight
        if (t < 23) asm volatile("s_waitcnt vmcnt(4)" ::: "memory");
        else        asm volatile("s_waitcnt vmcnt(0)" ::: "memory");
        __builtin_amdgcn_s_barrier();
        if (t < 22) STAGE(t + 2, (t + 2) % 3);
        asm volatile("" ::: "memory");

        const short* S  = &lds[t % 3][0];
        const float* Af = (const float*)S;           // A region (f32 planes)
        const int rowA  = wm * 16 + lm;
        f32x4 a0 = *(const f32x4*)(Af + ((lg * 2    ) * 32 + rowA) * 4);
        f32x4 a1 = *(const f32x4*)(Af + ((lg * 2 + 1) * 32 + rowA) * 4);
        short8 af;
        #pragma unroll
        for (int e = 0; e < 4; e++) { af[e] = f2bf(a0[e]); af[4 + e] = f2bf(a1[e]); }

        short8 bf[6];
        #pragma unroll
        for (int j = 0; j < 6; j++) {
            int rB = wn * 96 + j * 16 + lm;
            bf[j] = *(const short8*)&S[2048 + (lg * 192 + rB) * 8];
        }
        #pragma unroll
        for (int j = 0; j < 6; j++)
            acc[j] = __builtin_amdgcn_mfma_f32_16x16x32_bf16(af, bf[j], acc[j], 0, 0, 0);
    }

    // Epilogue (verified): bias, temporal res via shfl, gelu, bf16 store.
    const int g1 = lg & 1;
    #pragma unroll
    for (int j = 0; j < 6; j++) {
        const int c = wn * 96 + j * 16 + lm;
        const float b1c = b1[c];
        const float cw0 = conv_w[c * 3 + 0];
        const float cw1 = conv_w[c * 3 + 1];
        const float cw2 = conv_w[c * 3 + 2];
        const float cb  = conv_b[c];
        float hv[4];
        #pragma unroll
        for (int r = 0; r < 4; r++) hv[r] = acc[j][r] + b1c;
        float partial = 0.f;
        #pragma unroll
        for (int r = 0; r < 4; r++) {
            const int t = g1 * 4 + r;
            const float tf = (float)t;
            float coef = tf * cw1 - (7.0f - tf);
            if (t <= 6) coef += (tf + 1.0f) * cw0;
            if (t >= 1) coef += (tf - 1.0f) * cw2;
            partial += coef * hv[r];
        }
        const float full = partial + __shfl_xor(partial, 16);
        const float res = cb + full * (1.0f / 28.0f);
        const int row = R0 + wm * 16 + lg * 4;
        #pragma unroll
        for (int r = 0; r < 4; r++)
            gq[(size_t)(row + r) * CA + c] = f2bf(gelu_exact(hv[r] + res));
        if (l == 1) {                                // out token 0 = gelu(h[l=1]) (no res)
            #pragma unroll
            for (int r = 0; r < 4; r++)
                gq[(size_t)(row - 128 + r) * CA + c] = f2bf(gelu_exact(hv[r]));
        }
    }
}

// ---------------------------------------------------------------------------
// GEMM2: out = x + g @ w2 + b2. M=25216, K=192, N=768. BK=64 -> 3 iters.
// Full-DMA staging, 2 buffers (24KB each: A 8KB + B 16KB), 1-iter lead,
// vmcnt(0) + raw s_barrier once per iter (the wait is for DMA issued a full
// compute phase earlier). Both-sides chunk swizzle. (Unchanged; passed R3/R4.)
// BM=64, BN=128 -> grid (394, 6). 4 waves 2m x 2n, wave tile 32x64.
// ---------------------------------------------------------------------------
__global__ __launch_bounds__(256, 2) void gemm2_kernel(
        const short* __restrict__ gq, const short* __restrict__ w2T,
        const float* __restrict__ b2, const float* __restrict__ x,
        float* __restrict__ out) {
    __shared__ __align__(16) short lds[2][12288];   // per stage: A[0..4095], B[4096..12287]

    const int tid = threadIdx.x;
    const int m0 = blockIdx.x * 64;
    const int n0 = blockIdx.y * 128;
    const int wave = tid >> 6, lane = tid & 63;
    const int wm = wave >> 1, wn = wave & 1;
    const int lm = lane & 15, lg = lane >> 4;

    // 24 DMA instrs per stage (A:8, B:16), 6 per wave. s6 = wave*6+j.
    const short* src[6];
    int loff[6];
    #pragma unroll
    for (int j = 0; j < 6; j++) {
        int s6 = wave * 6 + j;
        if (s6 < 8) {            // A region, m in [0,64)
            int idx = s6 * 64 + lane;
            int m = idx >> 3, q = (idx & 7) ^ (m & 7);
            src[j]  = gq + (size_t)(m0 + m) * CA + q * 8;
            loff[j] = s6 * 512;
        } else {                 // B region, m in [0,128)
            int idx = (s6 - 8) * 64 + lane;
            int m = idx >> 3, q = (idx & 7) ^ (m & 7);
            src[j]  = w2T + (size_t)(n0 + m) * CA + q * 8;
            loff[j] = 4096 + (s6 - 8) * 512;
        }
    }

    f32x4 acc[2][4] = {};

    auto STAGE = [&](int t, int buf) {
        #pragma unroll
        for (int j = 0; j < 6; j++)
            ld16(&lds[buf][loff[j]], src[j] + t * 64);
    };

    STAGE(0, 0);

    #pragma unroll
    for (int t = 0; t < 3; t++) {
        asm volatile("s_waitcnt vmcnt(0)" ::: "memory");
        __builtin_amdgcn_s_barrier();
        if (t < 2) STAGE(t + 1, (t + 1) & 1);

        const short* A = &lds[t & 1][0];
        const short* B = &lds[t & 1][4096];
        #pragma unroll
        for (int kk = 0; kk < 2; kk++) {
            const int c = kk * 4 + lg;
            short8 af[2], bf[4];
            #pragma unroll
            for (int i2 = 0; i2 < 2; i2++) {
                int r = wm * 32 + i2 * 16 + lm;
                af[i2] = *(const short8*)&A[(r * 8 + (c ^ (r & 7))) * 8];
            }
            #pragma unroll
            for (int j = 0; j < 4; j++) {
                int rB = wn * 64 + j * 16 + lm;
                bf[j] = *(const short8*)&B[(rB * 8 + (c ^ (rB & 7))) * 8];
            }
            #pragma unroll
            for (int i2 = 0; i2 < 2; i2++)
                #pragma unroll
                for (int j = 0; j < 4; j++)
                    acc[i2][j] = __builtin_amdgcn_mfma_f32_16x16x32_bf16(af[i2], bf[j], acc[i2][j], 0, 0, 0);
        }
    }

    #pragma unroll
    for (int i2 = 0; i2 < 2; i2++) {
        const int row0 = m0 + wm * 32 + i2 * 16 + lg * 4;
        #pragma unroll
        for (int j = 0; j < 4; j++) {
            const int col = n0 + wn * 64 + j * 16 + lm;
            const float bias = b2[col];
            #pragma unroll
            for (int r = 0; r < 4; r++) {
                const size_t idx = (size_t)(row0 + r) * DIM + col;
                out[idx] = acc[i2][j][r] + x[idx] + bias;
            }
        }
    }
}

// ---------------------------------------------------------------------------
extern "C" void kernel_launch(void* const* d_in, const int* in_sizes, int n_in,
                              void* d_out, int out_size, void* d_ws, size_t ws_size,
                              hipStream_t stream) {
    (void)in_sizes; (void)n_in; (void)out_size; (void)ws_size;
    const float* x      = (const float*)d_in[0];
    const float* w1     = (const float*)d_in[1];
    const float* b1     = (const float*)d_in[2];
    const float* conv_w = (const float*)d_in[3];
    const float* conv_b = (const float*)d_in[4];
    const float* w2     = (const float*)d_in[5];
    const float* b2     = (const float*)d_in[6];
    float* out = (float*)d_out;

    char* ws = (char*)d_ws;
    short* g   = (short*)ws;                           // 25216*192*2 = 9,682,944 B
    short* w1T = (short*)(ws + 9682944);               // 294,912 B
    short* w2T = (short*)(ws + 9682944 + 294912);      // 294,912 B

    prep_kernel<<<(CA * DIM + 255) / 256, 256, 0, stream>>>(w1, w2, w1T, w2T);
    gemm1_fused<<<784, 256, 0, stream>>>(x, w1T, b1, conv_w, conv_b, g);
    gemm2_kernel<<<dim3(394, 6), 256, 0, stream>>>(g, w2T, b2, x, out);
}